// Round 3
// 579.276 us; speedup vs baseline: 1.1185x; 1.1185x over previous
//
#include <hip/hip_runtime.h>

typedef unsigned short u16;
typedef unsigned int u32;
typedef unsigned long long u64;

#define NID 25
// B*T=8, C_sem=512, C_ins=64, HP=WP=64 -> 4096 half-res px per bt.

// ---- workspace layout (bytes) ----
// [0,64)         : sc u64[8]: 0 align*2^32, 1 valid_cnt, 2 smem*2^32,
//                  3 mask_cnt, 4 intra*2^32, 5 insmem*2^32
// [64,68)        : flag i32 (1 = inputs are bf16, 0 = fp32)
// [256,1056)     : cnts i32[200]
// [4096,413696)  : sem_sums i32[200*512]  (scale 2^16)
// [413696,464896): ins_sums i32[200*64]   (scale 2^16)
// [466944,598016): ss i32[8*4096] (scale 2^20) — dead after k_p1b, overlaps proto_sem
// [466944,876544): proto_sem f32[200*512]  (written by k_p5, after ss is dead)
// [876544,927744): proto_ins f32[200*64]
// [927744,928544): valid_tab i32[200]
//   memset-zero region = [0,598016)

#define SC16  65536.0f
#define ISC16 (1.0f/65536.0f)
#define SC20  1048576.0f
#define ISC20 (1.0f/1048576.0f)
#define SC32  4294967296.0f

__device__ __forceinline__ float bf2f(u16 h){ return __uint_as_float(((u32)h) << 16); }
__device__ __forceinline__ u16 f2bf(float f){
  u32 u = __float_as_uint(f);
  u32 r = u + 0x7fffu + ((u >> 16) & 1u);
  return (u16)(r >> 16);
}

template<bool BF>
__device__ __forceinline__ float LD(const void* p, size_t i){
  if constexpr (BF) return bf2f(((const u16*)p)[i]);
  else return ((const float*)p)[i];
}
template<bool BF>
__device__ __forceinline__ float2 LD2(const void* p, size_t i){ // elems i,i+1 (i even)
  if constexpr (BF){
    ushort2 v = *(const ushort2*)((const u16*)p + i);
    return make_float2(bf2f(v.x), bf2f(v.y));
  } else {
    return *(const float2*)((const float*)p + i);
  }
}
template<bool BF>
__device__ __forceinline__ float4 LD4(const void* p, size_t i){ // elems i..i+3 (i%4==0)
  if constexpr (BF){
    ushort4 v = *(const ushort4*)((const u16*)p + i);
    return make_float4(bf2f(v.x), bf2f(v.y), bf2f(v.z), bf2f(v.w));
  } else {
    return *(const float4*)((const float*)p + i);
  }
}

// ---------------------------------------------------------------------------
// Probe: decide bf16 vs fp32 from raw bits of refined_sem.
// ---------------------------------------------------------------------------
__global__ __launch_bounds__(256) void k_probe(const u32* __restrict__ x,
                                               int* __restrict__ flag){
  __shared__ int cnt;
  if (threadIdx.x == 0) cnt = 0;
  __syncthreads();
  int c = 0;
  for (int i = threadIdx.x; i < 1024; i += 256){
    u32 e = (x[i] >> 7) & 0xffu;
    c += (e >= 100 && e <= 140) ? 1 : 0;
  }
  atomicAdd(&cnt, c);
  __syncthreads();
  if (threadIdx.x == 0) *flag = (cnt >= 600) ? 1 : 0;
}

// ---------------------------------------------------------------------------
// P1a: stream lseg_gt once, 8B/lane vector loads. Per block: one half-row
// (64 half-px) x 64 channels. Compute 2x2 means, accumulate per-px sum(m^2)
// (fixed point 2^20) -> global ss[bt*4096+px] via i32 atomics.
// grid (64 rows, 8 chgroups, 8 bt) x 256 = 4096 blocks; tiny LDS.
// ---------------------------------------------------------------------------
template<bool BF>
__device__ void p1a_body(const void* lg, int* __restrict__ ss){
  __shared__ int ps[64];
  const int t = threadIdx.x;
  const int hr = blockIdx.x;      // half-row 0..63
  const int cg = blockIdx.y;      // channel group 0..7
  const int bt = blockIdx.z;      // 0..7
  const int q2 = t & 31;          // half-px pair (2q2, 2q2+1)
  const int cw = t >> 5;          // 0..7, owns 8 channels
  if (t < 64) ps[t] = 0;
  __syncthreads();
  float s0 = 0.f, s1 = 0.f;
  const int c0 = cg*64 + cw*8;
  #pragma unroll
  for (int k = 0; k < 8; ++k){
    const size_t o = ((size_t)(bt*512 + c0 + k) << 14) + (hr << 8) + (q2 << 2);
    float4 a = LD4<BF>(lg, o);          // full row 2*hr, cols 4q2..4q2+3
    float4 b = LD4<BF>(lg, o + 128);    // full row 2*hr+1
    const float m0 = (a.x + a.y + b.x + b.y) * 0.25f;
    const float m1 = (a.z + a.w + b.z + b.w) * 0.25f;
    s0 += m0*m0; s1 += m1*m1;
  }
  atomicAdd(&ps[q2*2],     (int)rintf(s0 * SC20));
  atomicAdd(&ps[q2*2 + 1], (int)rintf(s1 * SC20));
  __syncthreads();
  if (t < 64){
    const int v = ps[t];
    if (v) atomicAdd(&ss[(bt << 12) + (hr << 6) + t], v);
  }
}
__global__ __launch_bounds__(256) void k_p1a(const void* lg, int* ss,
                                             const int* flag){
  if (*flag) p1a_body<true>(lg, ss);
  else       p1a_body<false>(lg, ss);
}

// ---------------------------------------------------------------------------
// P1b: re-read lseg_gt (L3-resident now), recompute means, scale by
// SC16/sqrt(ss) and segment-accumulate into LDS sums[4][25][129] (pad 129 ->
// distinct ids hit distinct banks). Also id histogram -> cnts.
// grid (32 px-blocks, 8 bt) x 512. 128 px x 512 ch per block.
// ---------------------------------------------------------------------------
template<bool BF>
__device__ void p1b_body(const void* lg, const int* __restrict__ im,
                         const int* __restrict__ ss,
                         int* __restrict__ sem_sums, int* __restrict__ cnts){
  __shared__ int sums[4*25*129];   // 51.6 KB
  __shared__ float invl[128];
  __shared__ int hist[NID];
  const int t = threadIdx.x;
  const int bt = blockIdx.y;
  const int pxb = blockIdx.x * 128;
  const int q = t & 127;           // px within block
  const int cw = t >> 7;           // 0..3, owns 128 channels
  for (int k = t; k < 4*25*129; k += 512) sums[k] = 0;
  if (t < NID) hist[t] = 0;
  const int p = pxb + q;           // 0..4095
  const int id = im[(bt << 14) + ((p >> 6) << 8) + ((p & 63) << 1)];
  if (t < 128){
    const float sf = (float)ss[(bt << 12) + pxb + t] * ISC20;
    invl[t] = SC16 / fmaxf(sqrtf(sf), 1e-12f);
  }
  __syncthreads();
  if (t < 128) atomicAdd(&hist[id], 1);
  const float inv = invl[q];
  const size_t pbase = ((size_t)(bt*512 + cw*128) << 14)
                     + ((p >> 6) << 8) + ((p & 63) << 1);
  int* dst = &sums[(cw*25 + id)*129];
  #pragma unroll 8
  for (int k = 0; k < 128; ++k){
    const size_t o = pbase + ((size_t)k << 14);
    float2 a = LD2<BF>(lg, o);
    float2 b = LD2<BF>(lg, o + 128);
    const float m = (a.x + a.y + b.x + b.y) * 0.25f;
    atomicAdd(&dst[k], (int)rintf(m * inv));
  }
  __syncthreads();
  for (int k = t; k < 25*512; k += 512){
    const int id2 = k >> 9, c2 = k & 511, cw2 = c2 >> 7, k2 = c2 & 127;
    const int v = sums[(cw2*25 + id2)*129 + k2];
    if (v) atomicAdd(&sem_sums[(bt*NID + id2)*512 + c2], v);
  }
  if (t < NID && hist[t] > 0) atomicAdd(&cnts[bt*NID + t], hist[t]);
}
__global__ __launch_bounds__(512) void k_p1b(const void* lg, const int* im,
    const int* ss, int* sem_sums, int* cnts, const int* flag){
  if (*flag) p1b_body<true>(lg, im, ss, sem_sums, cnts);
  else       p1b_body<false>(lg, im, ss, sem_sums, cnts);
}

// ---------------------------------------------------------------------------
// P4: instance segment sums. grid 256 x 256; 128 px, 2 ch-halves of 32.
// ---------------------------------------------------------------------------
template<bool BF>
__device__ void p4_body(const void* ri, const int* __restrict__ im,
                        int* __restrict__ ins_sums){
  __shared__ int   sums[2*25*33];
  __shared__ float parts[2][128];
  const int t = threadIdx.x;
  const int pb = blockIdx.x * 128;
  const int bt = pb >> 12;
  const int h = t >> 7, q = t & 127;
  const int p = (pb + q) & 4095;
  const int id = im[(bt << 14) + ((p >> 6) << 8) + ((p & 63) << 1)];
  for (int k = t; k < 2*25*33; k += 256) sums[k] = 0;
  float vals[32];
  float ffh = 0.f;
  #pragma unroll
  for (int cc = 0; cc < 32; ++cc){
    float v = LD<BF>(ri, (size_t)(bt*64 + h*32 + cc)*4096 + p);
    vals[cc] = v; ffh += v*v;
  }
  parts[h][q] = ffh;
  __syncthreads();
  const float inv = SC16 / fmaxf(sqrtf(parts[0][q] + parts[1][q]), 1e-12f);
  int* dst = &sums[h*825 + id*33];
  #pragma unroll
  for (int cc = 0; cc < 32; ++cc) atomicAdd(&dst[cc], (int)rintf(vals[cc]*inv));
  __syncthreads();
  for (int k = t; k < 1600; k += 256){
    const int id2 = k >> 6, c2 = k & 63, h2 = c2 >> 5, cc2 = c2 & 31;
    const int v = sums[h2*825 + id2*33 + cc2];
    if (v) atomicAdd(&ins_sums[(bt*NID + id2)*64 + c2], v);
  }
}
__global__ __launch_bounds__(256) void k_p4(const void* ri, const int* im,
    int* ins_sums, const int* flag){
  if (*flag) p4_body<true>(ri, im, ins_sums);
  else       p4_body<false>(ri, im, ins_sums);
}

// ---------------------------------------------------------------------------
// P5: normalize prototypes + validity. blocks 0..49 sem, 50..99 ins.
// ---------------------------------------------------------------------------
__global__ __launch_bounds__(256) void k_p5(const int* __restrict__ sem_sums,
    const int* __restrict__ ins_sums, const int* __restrict__ cnts,
    float* __restrict__ proto_sem, float* __restrict__ proto_ins,
    int* __restrict__ valid_tab){
  const int wg = blockIdx.x*4 + (threadIdx.x >> 6);
  const int l  = threadIdx.x & 63;
  if (blockIdx.x < 50){
    const int seg = wg;                       // 0..199
    float v[8]; float ss = 0.f;
    const size_t base = (size_t)seg*512 + l;
    #pragma unroll
    for (int k = 0; k < 8; ++k){
      v[k] = (float)sem_sums[base + 64*k] * ISC16;
      ss += v[k]*v[k];
    }
    for (int m = 1; m < 64; m <<= 1) ss += __shfl_xor(ss, m, 64);
    const float inv = 1.f / fmaxf(sqrtf(ss), 1e-12f);
    #pragma unroll
    for (int k = 0; k < 8; ++k) proto_sem[base + 64*k] = v[k]*inv;
    if (l == 0) valid_tab[seg] = (cnts[seg] >= 2 && (seg % NID) != 0) ? 1 : 0;
  } else {
    const int seg = wg - 200;
    float v = (float)ins_sums[(size_t)seg*64 + l] * ISC16;
    float ss = v*v;
    for (int m = 1; m < 64; m <<= 1) ss += __shfl_xor(ss, m, 64);
    proto_ins[(size_t)seg*64 + l] = v * (1.f / fmaxf(sqrtf(ss), 1e-12f));
  }
}

// ---------------------------------------------------------------------------
// P3: fused sem-align + sem-memory. grid 512 x 256; 64 px per block.
// Each lane owns a px PAIR (u32 = 2 bf16 per load), 8 ch-groups of 64.
// ---------------------------------------------------------------------------
template<bool BF>
__device__ void p3_body(const void* rs, const void* ms, const void* mmask,
    const int* __restrict__ im, const float* __restrict__ proto_sem,
    const int* __restrict__ valid_tab, u64* __restrict__ sc){
  __shared__ float protoT[25*513];     // 51.3 KB
  __shared__ float4 parts[8][64];      // 8 KB
  __shared__ int vt[NID];
  const int t = threadIdx.x;
  const int pb = blockIdx.x * 64;
  const int bt = pb >> 12;
  const int w  = t >> 5;               // 0..7 ch-group (64 ch)
  const int l2 = t & 31;               // px pair
  for (int f = t; f < 12800; f += 256){
    const int id2 = f >> 9, c2 = f & 511;
    protoT[id2*513 + c2] = proto_sem[(size_t)(bt*NID + id2)*512 + c2];
  }
  if (t < NID) vt[t] = valid_tab[bt*NID + t];
  __syncthreads();
  const int p0 = (pb & 4095) + 2*l2;
  const int p1 = p0 + 1;
  const int id0 = im[(bt << 14) + ((p0 >> 6) << 8) + ((p0 & 63) << 1)];
  const int id1 = im[(bt << 14) + ((p1 >> 6) << 8) + ((p1 & 63) << 1)];
  const size_t cbase = (size_t)(bt*512 + w*64)*4096 + p0;
  const float* pr0 = &protoT[id0*513 + w*64];
  const float* pr1 = &protoT[id1*513 + w*64];
  float pp0=0.f,pp1=0.f,pm0=0.f,pm1=0.f,mm0=0.f,mm1=0.f,pd0=0.f,pd1=0.f;
  #pragma unroll 8
  for (int cc = 0; cc < 64; ++cc){
    float2 pv = LD2<BF>(rs, cbase + (size_t)cc*4096);
    float2 mv = LD2<BF>(ms, cbase + (size_t)cc*4096);
    pp0 += pv.x*pv.x; pp1 += pv.y*pv.y;
    mm0 += mv.x*mv.x; mm1 += mv.y*mv.y;
    pm0 += pv.x*mv.x; pm1 += pv.y*mv.y;
    pd0 += pv.x*pr0[cc]; pd1 += pv.y*pr1[cc];
  }
  parts[w][2*l2]   = make_float4(pp0, pm0, mm0, pd0);
  parts[w][2*l2+1] = make_float4(pp1, pm1, mm1, pd1);
  __syncthreads();
  if (t < 64){
    float ppn=0.f, pm=0.f, mm=0.f, pd=0.f;
    #pragma unroll
    for (int k = 0; k < 8; ++k){
      float4 f4 = parts[k][t];
      ppn += f4.x; pm += f4.y; mm += f4.z; pd += f4.w;
    }
    const int g = pb + t;
    const int p = g & 4095;
    const int id = im[(bt << 14) + ((p >> 6) << 8) + ((p & 63) << 1)];
    const float npn = fmaxf(sqrtf(ppn), 1e-12f);
    const int vld = vt[id];
    float a_i = vld ? (1.f - pd/npn) : 0.f;
    float vc  = vld ? 1.f : 0.f;
    float mkv = LD<BF>(mmask, g);
    const float nmn = fmaxf(sqrtf(mm), 1e-12f);
    float s_i = mkv * (1.f - pm/(npn*nmn));
    for (int m = 1; m < 64; m <<= 1){
      a_i += __shfl_xor(a_i, m, 64);
      vc  += __shfl_xor(vc,  m, 64);
      s_i += __shfl_xor(s_i, m, 64);
      mkv += __shfl_xor(mkv, m, 64);
    }
    if (t == 0){
      long long v0 = llrintf(a_i * SC32);
      long long v2 = llrintf(s_i * SC32);
      if (v0) atomicAdd(&sc[0], (u64)v0);
      if (vc != 0.f) atomicAdd(&sc[1], (u64)llrintf(vc));
      if (v2) atomicAdd(&sc[2], (u64)v2);
      if (mkv != 0.f) atomicAdd(&sc[3], (u64)llrintf(mkv));
    }
  }
}
__global__ __launch_bounds__(256) void k_p3(const void* rs, const void* ms,
    const void* mmask, const int* im, const float* proto_sem,
    const int* valid_tab, u64* sc, const int* flag){
  if (*flag) p3_body<true>(rs, ms, mmask, im, proto_sem, valid_tab, sc);
  else       p3_body<false>(rs, ms, mmask, im, proto_sem, valid_tab, sc);
}

// ---------------------------------------------------------------------------
// P6: fused ins-intra + ins-memory. grid 256 x 256; 128 px per block.
// Each lane owns a px pair, 4 ch-groups of 16.
// ---------------------------------------------------------------------------
template<bool BF>
__device__ void p6_body(const void* ri, const void* mi, const void* mmask,
    const int* __restrict__ im, const float* __restrict__ proto_ins,
    const int* __restrict__ valid_tab, u64* __restrict__ sc){
  __shared__ float protoT[25*65];
  __shared__ float4 parts[4][128];     // 8 KB
  __shared__ int vt[NID];
  const int t = threadIdx.x;
  const int pb = blockIdx.x * 128;
  const int bt = pb >> 12;
  const int h2 = t >> 6;               // 0..3 ch-group (16 ch)
  const int q2 = t & 63;               // px pair
  for (int f = t; f < 1600; f += 256){
    const int id2 = f >> 6, c2 = f & 63;
    protoT[id2*65 + c2] = proto_ins[(size_t)(bt*NID + id2)*64 + c2];
  }
  if (t < NID) vt[t] = valid_tab[bt*NID + t];
  __syncthreads();
  const int p0 = (pb & 4095) + 2*q2;
  const int p1 = p0 + 1;
  const int id0 = im[(bt << 14) + ((p0 >> 6) << 8) + ((p0 & 63) << 1)];
  const int id1 = im[(bt << 14) + ((p1 >> 6) << 8) + ((p1 & 63) << 1)];
  const size_t cbase = (size_t)(bt*64 + h2*16)*4096 + p0;
  const float* pr0 = &protoT[id0*65 + h2*16];
  const float* pr1 = &protoT[id1*65 + h2*16];
  float ff0=0.f,ff1=0.f,fm0=0.f,fm1=0.f,m20=0.f,m21=0.f,fd0=0.f,fd1=0.f;
  #pragma unroll
  for (int cc = 0; cc < 16; ++cc){
    float2 fv = LD2<BF>(ri, cbase + (size_t)cc*4096);
    float2 mv = LD2<BF>(mi, cbase + (size_t)cc*4096);
    ff0 += fv.x*fv.x; ff1 += fv.y*fv.y;
    m20 += mv.x*mv.x; m21 += mv.y*mv.y;
    fm0 += fv.x*mv.x; fm1 += fv.y*mv.y;
    fd0 += fv.x*pr0[cc]; fd1 += fv.y*pr1[cc];
  }
  parts[h2][2*q2]   = make_float4(ff0, fm0, m20, fd0);
  parts[h2][2*q2+1] = make_float4(ff1, fm1, m21, fd1);
  __syncthreads();
  if (t < 128){
    float ff=0.f, fm=0.f, m2=0.f, fd=0.f;
    #pragma unroll
    for (int k = 0; k < 4; ++k){
      float4 f4 = parts[k][t];
      ff += f4.x; fm += f4.y; m2 += f4.z; fd += f4.w;
    }
    const int g = pb + t;
    const int p = g & 4095;
    const int id = im[(bt << 14) + ((p >> 6) << 8) + ((p & 63) << 1)];
    const float nf = fmaxf(sqrtf(ff), 1e-12f);
    float ii = vt[id] ? (1.f - fd/nf) : 0.f;
    const float mkv = LD<BF>(mmask, g);
    const float nm = fmaxf(sqrtf(m2), 1e-12f);
    float mi_ = mkv * (1.f - fm/(nf*nm));
    for (int m = 1; m < 64; m <<= 1){
      ii  += __shfl_xor(ii,  m, 64);
      mi_ += __shfl_xor(mi_, m, 64);
    }
    if ((t & 63) == 0){
      long long v4 = llrintf(ii  * SC32);
      long long v5 = llrintf(mi_ * SC32);
      if (v4) atomicAdd(&sc[4], (u64)v4);
      if (v5) atomicAdd(&sc[5], (u64)v5);
    }
  }
}
__global__ __launch_bounds__(256) void k_p6(const void* ri, const void* mi,
    const void* mmask, const int* im, const float* proto_ins,
    const int* valid_tab, u64* sc, const int* flag){
  if (*flag) p6_body<true>(ri, mi, mmask, im, proto_ins, valid_tab, sc);
  else       p6_body<false>(ri, mi, mmask, im, proto_ins, valid_tab, sc);
}

// ---------------------------------------------------------------------------
// F: inter-prototype hinge + final combine. 1 block. Dual-format scalar write.
// ---------------------------------------------------------------------------
__global__ __launch_bounds__(256) void k_f(const float* __restrict__ proto_ins,
    const int* __restrict__ valid_tab, const u64* __restrict__ sc,
    u32* __restrict__ out){
  __shared__ float P[25*65];
  __shared__ int vt[NID];
  __shared__ float red[8];
  const int t = threadIdx.x;
  float hsum = 0.f, pcnt = 0.f;
  for (int bt = 0; bt < 8; ++bt){
    __syncthreads();
    for (int f = t; f < 1600; f += 256){
      const int id2 = f >> 6, c2 = f & 63;
      P[id2*65 + c2] = proto_ins[bt*1600 + f];
    }
    if (t < NID) vt[t] = valid_tab[bt*NID + t];
    __syncthreads();
    for (int kl = t; kl < 625; kl += 256){
      const int k = kl / 25, l = kl - k*25;
      if (k != l && vt[k] && vt[l]){
        float s = 0.f;
        #pragma unroll
        for (int c = 0; c < 64; ++c) s += P[k*65 + c] * P[l*65 + c];
        hsum += fmaxf(s - 0.2f, 0.f);
        pcnt += 1.f;
      }
    }
  }
  for (int m = 1; m < 64; m <<= 1){
    hsum += __shfl_xor(hsum, m, 64);
    pcnt += __shfl_xor(pcnt, m, 64);
  }
  __syncthreads();
  if ((t & 63) == 0){ red[t >> 6] = hsum; red[4 + (t >> 6)] = pcnt; }
  __syncthreads();
  if (t == 0){
    const float inter = red[0]+red[1]+red[2]+red[3];
    const float pc    = red[4]+red[5]+red[6]+red[7];
    const double S = 1.0 / 4294967296.0;
    const double asum = (double)(long long)sc[0] * S;
    const double vcnt = (double)(long long)sc[1];
    const double ssum = (double)(long long)sc[2] * S;
    const double mcnt = (double)(long long)sc[3];
    const double isum = (double)(long long)sc[4] * S;
    const double msum = (double)(long long)sc[5] * S;
    const double align = asum / (vcnt > 1.0 ? vcnt : 1.0);
    const double smem  = ssum / (mcnt > 1.0 ? mcnt : 1.0);
    const double intra = isum / (vcnt > 1.0 ? vcnt : 1.0);
    const double imem  = msum / (mcnt > 1.0 ? mcnt : 1.0);
    const double obj = 0.5*align + smem + intra + (double)(inter / fmaxf(pc, 1.f)) + imem;
    const u32 b = (u32)f2bf((float)obj);
    out[0] = (b << 16) | b;
  }
}

extern "C" void kernel_launch(void* const* d_in, const int* in_sizes, int n_in,
                              void* d_out, int out_size, void* d_ws, size_t ws_size,
                              hipStream_t stream){
  const void* rs    = d_in[0];            // refined_sem  [8,512,4096]
  const void* ri    = d_in[1];            // refined_ins  [8,64,4096]
  const void* lg    = d_in[2];            // lseg_gt      [8,512,128,128]
  const void* ms    = d_in[3];            // mem_sem      [8,512,4096]
  const void* mi    = d_in[4];            // mem_ins      [8,64,4096]
  const void* mmask = d_in[5];            // mem_mask     [8,4096]
  const int*  im    = (const int*)d_in[6];// inst_mask    [8,128,128] int32

  char* ws = (char*)d_ws;
  u64*   sc        = (u64*)  ws;
  int*   flag      = (int*)  (ws + 64);
  int*   cnts      = (int*)  (ws + 256);
  int*   sem_sums  = (int*)  (ws + 4096);
  int*   ins_sums  = (int*)  (ws + 413696);
  int*   ss        = (int*)  (ws + 466944);   // overlaps proto_sem; dead by k_p5
  float* proto_sem = (float*)(ws + 466944);
  float* proto_ins = (float*)(ws + 876544);
  int*   valid_tab = (int*)  (ws + 927744);

  hipMemsetAsync(d_ws, 0, 598016, stream);
  k_probe<<<1, 256, 0, stream>>>((const u32*)rs, flag);
  k_p1a<<<dim3(64, 8, 8), 256, 0, stream>>>(lg, ss, flag);
  k_p1b<<<dim3(32, 8), 512, 0, stream>>>(lg, im, ss, sem_sums, cnts, flag);
  k_p4<<<256, 256, 0, stream>>>(ri, im, ins_sums, flag);
  k_p5<<<100, 256, 0, stream>>>(sem_sums, ins_sums, cnts, proto_sem, proto_ins, valid_tab);
  k_p3<<<512, 256, 0, stream>>>(rs, ms, mmask, im, proto_sem, valid_tab, sc, flag);
  k_p6<<<256, 256, 0, stream>>>(ri, mi, mmask, im, proto_ins, valid_tab, sc, flag);
  k_f<<<1, 256, 0, stream>>>(proto_ins, valid_tab, sc, (u32*)d_out);
}